// Round 11
// baseline (250.083 us; speedup 1.0000x reference)
//
#include <hip/hip_runtime.h>
#include <hip/hip_bf16.h>
#include <math.h>

#define N_USERS 50000
#define N_ITEMS 50000
#define NN      100000
#define E_PER_  400000
#define E_TOT   800000
#define FDIM    128
#define NH      4
#define HD      32
#define SCAN_CHUNK 1024
#define SCAN_NB    ((NN + SCAN_CHUNK - 1) / SCAN_CHUNK)   // 98
#define KQV_NB  ((N_USERS + 127) / 128)                   // 391 per side

typedef __attribute__((ext_vector_type(8))) short bfrag;   // 8 bf16 (4 VGPR)
typedef __attribute__((ext_vector_type(4))) float f32x4;

__device__ __forceinline__ float gelu_exact(float x) {
    return 0.5f * x * (1.0f + erff(x * 0.70710678118654752f));
}
__device__ __forceinline__ unsigned short f2bf(float f) {
    unsigned u = __float_as_uint(f);
    unsigned r = u + 0x7fffu + ((u >> 16) & 1u);
    return (unsigned short)(r >> 16);
}
__device__ __forceinline__ void unpack8(uint4 u, float* f) {
    f[0] = __uint_as_float(u.x << 16); f[1] = __uint_as_float(u.x & 0xffff0000u);
    f[2] = __uint_as_float(u.y << 16); f[3] = __uint_as_float(u.y & 0xffff0000u);
    f[4] = __uint_as_float(u.z << 16); f[5] = __uint_as_float(u.z & 0xffff0000u);
    f[6] = __uint_as_float(u.w << 16); f[7] = __uint_as_float(u.w & 0xffff0000u);
}
// fragment slot index for A-operand W (16B per lane): n = matrix row, k = contraction
__device__ __forceinline__ size_t wfrag_idx(int n, int k) {
    int ch = n >> 7, nt = (n >> 4) & 7, lr = n & 15;
    int ks = k >> 5, lg = (k >> 3) & 3, e = k & 7;
    return ((size_t)(((ch * 8 + nt) * 4 + ks) * 64 + lg * 16 + lr)) * 8 + e;
}

// ---------------------------------------------------------------------------
// Weight prep: fuse rel-transform into KQV weights; emit in MFMA frag layout.
// ---------------------------------------------------------------------------
__global__ void prep_kqv(
    const float* __restrict__ W_u, const float* __restrict__ b_u,
    const float* __restrict__ W_i, const float* __restrict__ b_i,
    const float* __restrict__ Wk_rel, const float* __restrict__ Wv_rel,
    unsigned short* __restrict__ F_u, float* __restrict__ bias_u,
    unsigned short* __restrict__ F_i, float* __restrict__ bias_i)
{
    const int et = blockIdx.x >= 384;
    const int n = blockIdx.x - et * 384;   // 0..383
    const int k = threadIdx.x;             // 0..127
    const float* W = et ? W_i : W_u;
    const float* b = et ? b_i : b_u;
    unsigned short* F = et ? F_i : F_u;
    float* bias_f = et ? bias_i : bias_u;
    float s;
    if (n < 128) {
        int h = n >> 5, e = n & 31;
        const float* wr = Wk_rel + (size_t)(h * 2 + et) * 1024 + e;
        const float* wc = W + (size_t)k * 384 + h * 32;
        s = 0.f;
        for (int d = 0; d < 32; ++d) s = fmaf(wc[d], wr[d * 32], s);
        if (k == 0) {
            float bs = 0.f;
            for (int d = 0; d < 32; ++d) bs = fmaf(b[h * 32 + d], wr[d * 32], bs);
            bias_f[n] = bs;
        }
    } else if (n < 256) {
        s = W[(size_t)k * 384 + n];
        if (k == 0) bias_f[n] = b[n];
    } else {
        int h = (n - 256) >> 5, e = (n - 256) & 31;
        const float* wr = Wv_rel + (size_t)(h * 2 + et) * 1024 + e;
        const float* wc = W + (size_t)k * 384 + 256 + h * 32;
        s = 0.f;
        for (int d = 0; d < 32; ++d) s = fmaf(wc[d], wr[d * 32], s);
        if (k == 0) {
            float bs = 0.f;
            for (int d = 0; d < 32; ++d) bs = fmaf(b[256 + h * 32 + d], wr[d * 32], bs);
            bias_f[n] = bs;
        }
    }
    F[wfrag_idx(n, k)] = f2bf(s);
}

// W_out[k][n] f32 -> frag layout bf16 (single 128-chunk)
__global__ void prep_wo(
    const float* __restrict__ W_u, unsigned short* __restrict__ F_u,
    const float* __restrict__ W_i, unsigned short* __restrict__ F_i)
{
    int i = blockIdx.x * blockDim.x + threadIdx.x;   // 0..2*16384
    int side = i >= 128 * 128;
    int j = i - side * 128 * 128;
    if (j >= 128 * 128) return;
    int n = j >> 7, k = j & 127;
    const float* W = side ? W_i : W_u;
    unsigned short* F = side ? F_i : F_u;
    F[wfrag_idx(n, k)] = f2bf(W[(size_t)k * 128 + n]);
}

// ---------------------------------------------------------------------------
// KQV GEMM, LDS-free. BM=128 (4 waves x 32 rows), N=384 in 3 chunks.
// ---------------------------------------------------------------------------
__global__ __launch_bounds__(256, 3) void kqv_mfma(
    const float* __restrict__ X_u, const unsigned short* __restrict__ F_u,
    const float* __restrict__ bias_u,
    const float* __restrict__ X_i, const unsigned short* __restrict__ F_i,
    const float* __restrict__ bias_i,
    unsigned short* __restrict__ kk_b,
    unsigned short* __restrict__ q_b,
    unsigned short* __restrict__ vv_b)
{
    const int t = threadIdx.x;
    const int side = blockIdx.x >= KQV_NB;
    const int m0 = (blockIdx.x - side * KQV_NB) * 128;
    const float* X = side ? X_i : X_u;
    const unsigned short* F = side ? F_i : F_u;
    const float* bias = side ? bias_i : bias_u;
    const int side_off = side ? N_USERS : 0;
    const int M = N_USERS;

    const int wave = t >> 6, lane = t & 63;
    const int lr = lane & 15, lg = lane >> 4;
    const int rbase = m0 + wave * 32;

    bfrag am[2][4];
    #pragma unroll
    for (int mt = 0; mt < 2; ++mt)
        #pragma unroll
        for (int ks = 0; ks < 4; ++ks) {
            int row = rbase + mt * 16 + lr;
            float4 a = make_float4(0.f, 0.f, 0.f, 0.f);
            float4 b4 = make_float4(0.f, 0.f, 0.f, 0.f);
            if (row < M) {
                const float* px = X + (size_t)row * 128 + ks * 32 + lg * 8;
                a  = *reinterpret_cast<const float4*>(px);
                b4 = *reinterpret_cast<const float4*>(px + 4);
            }
            uint4 pk;
            pk.x = (unsigned)f2bf(a.x)  | ((unsigned)f2bf(a.y)  << 16);
            pk.y = (unsigned)f2bf(a.z)  | ((unsigned)f2bf(a.w)  << 16);
            pk.z = (unsigned)f2bf(b4.x) | ((unsigned)f2bf(b4.y) << 16);
            pk.w = (unsigned)f2bf(b4.z) | ((unsigned)f2bf(b4.w) << 16);
            am[mt][ks] = *reinterpret_cast<bfrag*>(&pk);
        }

    #pragma unroll
    for (int ch = 0; ch < 3; ++ch) {
        f32x4 acc[2][8];
        const f32x4 zero = {0.f, 0.f, 0.f, 0.f};
        #pragma unroll
        for (int mt = 0; mt < 2; ++mt)
            #pragma unroll
            for (int nt = 0; nt < 8; ++nt) acc[mt][nt] = zero;

        bfrag bc[4], bn[4];
        #pragma unroll
        for (int ks = 0; ks < 4; ++ks)
            bc[ks] = *reinterpret_cast<const bfrag*>(
                F + ((size_t)((ch * 8 + 0) * 4 + ks) * 64 + lane) * 8);

        #pragma unroll
        for (int nt = 0; nt < 8; ++nt) {
            if (nt < 7) {
                #pragma unroll
                for (int ks = 0; ks < 4; ++ks)
                    bn[ks] = *reinterpret_cast<const bfrag*>(
                        F + ((size_t)((ch * 8 + nt + 1) * 4 + ks) * 64 + lane) * 8);
            }
            #pragma unroll
            for (int mt = 0; mt < 2; ++mt)
                #pragma unroll
                for (int ks = 0; ks < 4; ++ks)
                    acc[mt][nt] = __builtin_amdgcn_mfma_f32_16x16x32_bf16(
                        bc[ks], am[mt][ks], acc[mt][nt], 0, 0, 0);
            #pragma unroll
            for (int ks = 0; ks < 4; ++ks) bc[ks] = bn[ks];
        }

        unsigned short* arr = (ch == 0) ? kk_b : (ch == 1) ? q_b : vv_b;
        #pragma unroll
        for (int nt = 0; nt < 8; ++nt) {
            float4 bv = *reinterpret_cast<const float4*>(bias + ch * 128 + nt * 16 + lg * 4);
            #pragma unroll
            for (int mt = 0; mt < 2; ++mt) {
                int row = rbase + mt * 16 + lr;
                if (row < M) {
                    unsigned lo = (unsigned)f2bf(acc[mt][nt][0] + bv.x)
                                | ((unsigned)f2bf(acc[mt][nt][1] + bv.y) << 16);
                    unsigned hi = (unsigned)f2bf(acc[mt][nt][2] + bv.z)
                                | ((unsigned)f2bf(acc[mt][nt][3] + bv.w) << 16);
                    uint2 st = make_uint2(lo, hi);
                    *reinterpret_cast<uint2*>(
                        arr + (size_t)(side_off + row) * 128 + nt * 16 + lg * 4) = st;
                }
            }
        }
    }
}

// ---------------------------------------------------------------------------
// CSR build: histogram -> scan1 -> scan3(inline bsum prefix, emits int2 meta)
// -> fill
// ---------------------------------------------------------------------------
__device__ __forceinline__ void edge_src_dst(
    int e, const int* __restrict__ edge_ui, const int* __restrict__ edge_iu,
    int& src, int& dst)
{
    if (e < E_PER_) {
        src = edge_ui[e];
        dst = edge_ui[E_PER_ + e] + N_USERS;
    } else {
        int e2 = e - E_PER_;
        src = N_USERS + edge_iu[e2];
        dst = edge_iu[E_PER_ + e2];
    }
}

__global__ __launch_bounds__(256) void hist_kernel(
    const int* __restrict__ edge_ui, const int* __restrict__ edge_iu,
    int* __restrict__ cnt)
{
    int e = blockIdx.x * blockDim.x + threadIdx.x;
    if (e >= E_TOT) return;
    int src, dst;
    edge_src_dst(e, edge_ui, edge_iu, src, dst);
    atomicAdd(cnt + dst, 1);
}

__global__ __launch_bounds__(256) void scan1_kernel(
    const int* __restrict__ cnt, int* __restrict__ base, int* __restrict__ bsum)
{
    __shared__ int ssum[256];
    const int t = threadIdx.x;
    const int i0 = blockIdx.x * SCAN_CHUNK + t * 4;
    int v[4];
    #pragma unroll
    for (int j = 0; j < 4; ++j) v[j] = (i0 + j < NN) ? cnt[i0 + j] : 0;
    int tsum = v[0] + v[1] + v[2] + v[3];
    ssum[t] = tsum;
    __syncthreads();
    int run = tsum;
    for (int off = 1; off < 256; off <<= 1) {
        int o = (t >= off) ? ssum[t - off] : 0;
        __syncthreads();
        run += o;
        ssum[t] = run;
        __syncthreads();
    }
    int excl = run - tsum;
    int p = excl;
    #pragma unroll
    for (int j = 0; j < 4; ++j) {
        if (i0 + j < NN) base[i0 + j] = p;
        p += v[j];
    }
    if (t == 255) bsum[blockIdx.x] = run;
}

// scan3: adds chunk-prefix of bsum; writes cursor and packed (base,cnt) meta.
__global__ __launch_bounds__(256) void scan3_kernel(
    const int* __restrict__ base, const int* __restrict__ bsum,
    const int* __restrict__ cnt,
    int* __restrict__ cursor, int2* __restrict__ meta2)
{
    const int lane = threadIdx.x & 63;
    const int chunk = blockIdx.x >> 2;          // 256 threads, 1024-chunks
    int v0 = (lane < chunk) ? bsum[lane] : 0;
    int v1 = (64 + lane < chunk && 64 + lane < SCAN_NB) ? bsum[64 + lane] : 0;
    int s = v0 + v1;
    #pragma unroll
    for (int off = 1; off < 64; off <<= 1) s += __shfl_xor(s, off);
    int i = blockIdx.x * 256 + threadIdx.x;
    if (i < NN) {
        int b = base[i] + s;
        cursor[i] = b;
        meta2[i] = make_int2(b, cnt[i]);
    }
}

__global__ __launch_bounds__(256) void fill_kernel(
    const int* __restrict__ edge_ui, const int* __restrict__ edge_iu,
    int* __restrict__ cursor, int* __restrict__ esrc)
{
    int e = blockIdx.x * blockDim.x + threadIdx.x;
    if (e >= E_TOT) return;
    int src, dst;
    edge_src_dst(e, edge_ui, edge_iu, src, dst);
    int pos = atomicAdd(cursor + dst, 1);
    esrc[pos] = src;
}

// ---------------------------------------------------------------------------
// Fused attention v5: wave/node, 8 edges/round, NODE-LEVEL 2-deep pipeline.
// While computing node A: meta+q for node C issued, esrc+round1-gathers for
// node B already in flight (issued last iteration). Only c>16 tail serial.
// g=lane>>3 (edge slot), p=lane&7 (dims 16p..16p+15), head h=p>>1.
// Per-head dot = one shfl_xor(1). Reduce-scatter + gelu on all lanes.
// ---------------------------------------------------------------------------
__global__ __launch_bounds__(256) void attn_fused(
    const unsigned short* __restrict__ q_b, const unsigned short* __restrict__ kk_b,
    const unsigned short* __restrict__ vv_b,
    const int2* __restrict__ meta2, const int* __restrict__ esrc,
    const float* __restrict__ p_ui, const float* __restrict__ p_iu,
    unsigned short* __restrict__ oa)
{
    const int wid  = (blockIdx.x * blockDim.x + threadIdx.x) >> 6;
    const int lane = threadIdx.x & 63;
    const int nw   = (gridDim.x * blockDim.x) >> 6;
    const int g    = lane >> 3;      // edge slot 0..7
    const int p    = lane & 7;       // dims 16p..16p+15
    const int h    = p >> 1;         // head
    const float rsd = 0.17677669529663687f;   // 1/sqrt(32)
    const float pu = p_ui[h], pi = p_iu[h];
    const int EC = E_TOT - 1;

    if (wid >= NN) return;

    #define QA(nn)  (*reinterpret_cast<const uint4*>(q_b  + (size_t)(nn) * 128 + p * 16))
    #define QB(nn)  (*reinterpret_cast<const uint4*>(q_b  + (size_t)(nn) * 128 + p * 16 + 8))
    #define KA(ee)  (*reinterpret_cast<const uint4*>(kk_b + (size_t)(ee) * 128 + p * 16))
    #define KB(ee)  (*reinterpret_cast<const uint4*>(kk_b + (size_t)(ee) * 128 + p * 16 + 8))
    #define VA(ee)  (*reinterpret_cast<const uint4*>(vv_b + (size_t)(ee) * 128 + p * 16))
    #define VB(ee)  (*reinterpret_cast<const uint4*>(vv_b + (size_t)(ee) * 128 + p * 16 + 8))

    // ---- prologue: node A fully staged ----
    int n = wid;
    int2 mtA = meta2[n];
    uint4 qAa = QA(n), qAb = QB(n);
    int sA = mtA.x, cA = mtA.y;
    int j0A = (g < cA) ? g : 0;
    int e0A = esrc[min(sA + j0A, EC)];
    int e1A = esrc[min(sA + ((8 + g < cA) ? (8 + g) : j0A), EC)];
    uint4 kAa = KA(e0A), kAb = KB(e0A), vAa = VA(e0A), vAb = VB(e0A);

    // ---- node B staged ----
    int nB = n + nw;
    bool hasB = nB < NN;
    int sB = 0, cB = 0, e1B = 0;
    uint4 qBa{}, qBb{}, kBa{}, kBb{}, vBa{}, vBb{};
    if (hasB) {
        int2 mtB = meta2[nB];
        qBa = QA(nB); qBb = QB(nB);
        sB = mtB.x; cB = mtB.y;
        int j0 = (g < cB) ? g : 0;
        int e0B = esrc[min(sB + j0, EC)];
        e1B = esrc[min(sB + ((8 + g < cB) ? (8 + g) : j0), EC)];
        kBa = KA(e0B); kBb = KB(e0B); vBa = VA(e0B); vBb = VB(e0B);
    }

    for (;;) {
        // (1) issue meta+q for node C = nB + nw (2 ahead)
        const int nC = nB + nw;
        const bool hasC = hasB && (nC < NN);
        int2 mtC; uint4 qCa, qCb;
        if (hasC) { mtC = meta2[nC]; qCa = QA(nC); qCb = QB(nC); }

        // (2) issue round-2 gathers for current node (e1A resident)
        const bool has2 = cA > 8;
        uint4 k2a, k2b, v2a, v2b;
        if (has2) { k2a = KA(e1A); k2b = KB(e1A); v2a = VA(e1A); v2b = VB(e1A); }

        // (3) compute current node
        const float pr = (n >= N_USERS) ? pu : pi;
        float qf[16];
        unpack8(qAa, qf); unpack8(qAb, qf + 8);
        float l = 0.f;
        float acc[16];
        #pragma unroll
        for (int i = 0; i < 16; ++i) acc[i] = 0.f;

        {   // round 1 (gathers kA/vA arrived — issued one iteration ago)
            float kf[16];
            unpack8(kAa, kf); unpack8(kAb, kf + 8);
            float s = qf[0] * kf[0];
            #pragma unroll
            for (int i = 1; i < 16; ++i) s = fmaf(qf[i], kf[i], s);
            s += __shfl_xor(s, 1);
            float w = (g < cA) ? __expf(s * pr * rsd) : 0.f;
            l += w;
            float vf[16];
            unpack8(vAa, vf); unpack8(vAb, vf + 8);
            #pragma unroll
            for (int i = 0; i < 16; ++i) acc[i] = fmaf(w, vf[i], acc[i]);
        }
        if (has2) {   // round 2
            float kf[16];
            unpack8(k2a, kf); unpack8(k2b, kf + 8);
            float s = qf[0] * kf[0];
            #pragma unroll
            for (int i = 1; i < 16; ++i) s = fmaf(qf[i], kf[i], s);
            s += __shfl_xor(s, 1);
            float w = (8 + g < cA) ? __expf(s * pr * rsd) : 0.f;
            l += w;
            float vf[16];
            unpack8(v2a, vf); unpack8(v2b, vf + 8);
            #pragma unroll
            for (int i = 0; i < 16; ++i) acc[i] = fmaf(w, vf[i], acc[i]);
        }
        for (int j = 16; j < cA; j += 8) {   // rare tail (~1% of nodes)
            int jj = j + g;
            bool val = jj < cA;
            int e = esrc[sA + (val ? jj : 0)];
            uint4 ka = KA(e), kb = KB(e), va = VA(e), vb = VB(e);
            float kf[16];
            unpack8(ka, kf); unpack8(kb, kf + 8);
            float s = qf[0] * kf[0];
            #pragma unroll
            for (int i = 1; i < 16; ++i) s = fmaf(qf[i], kf[i], s);
            s += __shfl_xor(s, 1);
            float w = val ? __expf(s * pr * rsd) : 0.f;
            l += w;
            float vf[16];
            unpack8(va, vf); unpack8(vb, vf + 8);
            #pragma unroll
            for (int i = 0; i < 16; ++i) acc[i] = fmaf(w, vf[i], acc[i]);
        }

        // (4) per-head denominator over the 8 edge groups
        l += __shfl_xor(l, 8); l += __shfl_xor(l, 16); l += __shfl_xor(l, 32);

        // (5) reduce-scatter acc across groups
        const bool b2 = (g & 4) != 0;
        float k8[8];
        #pragma unroll
        for (int i = 0; i < 8; ++i) {
            float mine = b2 ? acc[8 + i] : acc[i];
            float send = b2 ? acc[i] : acc[8 + i];
            k8[i] = mine + __shfl_xor(send, 32);
        }
        const bool b1 = (g & 2) != 0;
        float k4r[4];
        #pragma unroll
        for (int i = 0; i < 4; ++i) {
            float mine = b1 ? k8[4 + i] : k8[i];
            float send = b1 ? k8[i] : k8[4 + i];
            k4r[i] = mine + __shfl_xor(send, 16);
        }
        const bool b0 = (g & 1) != 0;
        float k2r[2];
        #pragma unroll
        for (int i = 0; i < 2; ++i) {
            float mine = b0 ? k4r[2 + i] : k4r[i];
            float send = b0 ? k4r[i] : k4r[2 + i];
            k2r[i] = mine + __shfl_xor(send, 8);
        }
        float inv = 1.0f / (l + 1e-16f);
        unsigned pk = (unsigned)f2bf(gelu_exact(k2r[0] * inv))
                    | ((unsigned)f2bf(gelu_exact(k2r[1] * inv)) << 16);
        *reinterpret_cast<unsigned*>(oa + (size_t)n * 128 + p * 16 + 2 * g) = pk;

        if (!hasB) break;

        // (6) rotate A <- B, stage B <- C (meta arrived ~a compute-phase ago)
        n = nB;
        sA = sB; cA = cB; e1A = e1B;
        qAa = qBa; qAb = qBb;
        kAa = kBa; kAb = kBb; vAa = vBa; vAb = vBb;
        nB = nC; hasB = hasC;
        if (hasC) {
            qBa = qCa; qBb = qCb;
            sB = mtC.x; cB = mtC.y;
            int j0 = (g < cB) ? g : 0;
            int e0B = esrc[min(sB + j0, EC)];
            e1B = esrc[min(sB + ((8 + g < cB) ? (8 + g) : j0), EC)];
            kBa = KA(e0B); kBb = KB(e0B); vBa = VA(e0B); vBb = VB(e0B);
        }
    }
    #undef QA
    #undef QB
    #undef KA
    #undef KB
    #undef VA
    #undef VB
}

// ---------------------------------------------------------------------------
// Final GEMM, LDS-free (both sides): out = sg*(oa_gelu @ Wo + bo) + (1-sg)*x.
// R6 structure: dbuf weight frags, (256,3), no gelu (done in attn).
// ---------------------------------------------------------------------------
__global__ __launch_bounds__(256, 3) void final_mfma(
    const unsigned short* __restrict__ oa,   // [NN][128] bf16, gelu'd
    const float* __restrict__ x_u, const unsigned short* __restrict__ F_u,
    const float* __restrict__ bo_u, const float* __restrict__ skip_u,
    const float* __restrict__ x_i, const unsigned short* __restrict__ F_i,
    const float* __restrict__ bo_i, const float* __restrict__ skip_i,
    float* __restrict__ out)
{
    const int t = threadIdx.x;
    const int side = blockIdx.x >= KQV_NB;
    const int m0 = (blockIdx.x - side * KQV_NB) * 128;
    const float* x = side ? x_i : x_u;
    const unsigned short* F = side ? F_i : F_u;
    const float* bo = side ? bo_i : bo_u;
    const float* skip = side ? skip_i : skip_u;
    const int row_off = side ? N_USERS : 0;
    const int M = N_USERS;

    const int wave = t >> 6, lane = t & 63;
    const int lr = lane & 15, lg = lane >> 4;
    const int rbase = m0 + wave * 32;

    bfrag am[2][4];
    const bfrag bz = {0, 0, 0, 0, 0, 0, 0, 0};
    #pragma unroll
    for (int mt = 0; mt < 2; ++mt)
        #pragma unroll
        for (int ks = 0; ks < 4; ++ks) {
            int row = rbase + mt * 16 + lr;
            am[mt][ks] = (row < M)
                ? *reinterpret_cast<const bfrag*>(
                      oa + (size_t)(row_off + row) * 128 + ks * 32 + lg * 8)
                : bz;
        }

    f32x4 acc[2][8];
    const f32x4 zero = {0.f, 0.f, 0.f, 0.f};
    #pragma unroll
    for (int mt = 0; mt < 2; ++mt)
        #pragma unroll
        for (int nt = 0; nt < 8; ++nt) acc[mt][nt] = zero;

    bfrag bc[4], bn[4];
    #pragma unroll
    for (int ks = 0; ks < 4; ++ks)
        bc[ks] = *reinterpret_cast<const bfrag*>(
            F + ((size_t)(0 * 4 + ks) * 64 + lane) * 8);

    #pragma unroll
    for (int nt = 0; nt < 8; ++nt) {
        if (nt < 7) {
            #pragma unroll
            for (int ks = 0; ks < 4; ++ks)
                bn[ks] = *reinterpret_cast<const bfrag*>(
                    F + ((size_t)((nt + 1) * 4 + ks) * 64 + lane) * 8);
        }
        #pragma unroll
        for (int mt = 0; mt < 2; ++mt)
            #pragma unroll
            for (int ks = 0; ks < 4; ++ks)
                acc[mt][nt] = __builtin_amdgcn_mfma_f32_16x16x32_bf16(
                    bc[ks], am[mt][ks], acc[mt][nt], 0, 0, 0);
        #pragma unroll
        for (int ks = 0; ks < 4; ++ks) bc[ks] = bn[ks];
    }

    const float sg = 1.0f / (1.0f + expf(-skip[0]));
    #pragma unroll
    for (int nt = 0; nt < 8; ++nt) {
        float4 bv = *reinterpret_cast<const float4*>(bo + nt * 16 + lg * 4);
        #pragma unroll
        for (int mt = 0; mt < 2; ++mt) {
            int row = rbase + mt * 16 + lr;
            if (row < M) {
                float4 xv = *reinterpret_cast<const float4*>(
                    x + (size_t)row * 128 + nt * 16 + lg * 4);
                float4 res;
                res.x = sg * (acc[mt][nt][0] + bv.x) + (1.f - sg) * xv.x;
                res.y = sg * (acc[mt][nt][1] + bv.y) + (1.f - sg) * xv.y;
                res.z = sg * (acc[mt][nt][2] + bv.z) + (1.f - sg) * xv.z;
                res.w = sg * (acc[mt][nt][3] + bv.w) + (1.f - sg) * xv.w;
                *reinterpret_cast<float4*>(
                    out + (size_t)(row_off + row) * 128 + nt * 16 + lg * 4) = res;
            }
        }
    }
}

// ---------------------------------------------------------------------------
extern "C" void kernel_launch(void* const* d_in, const int* in_sizes, int n_in,
                              void* d_out, int out_size, void* d_ws, size_t ws_size,
                              hipStream_t stream)
{
    const float* x_user     = (const float*)d_in[0];
    const float* x_item     = (const float*)d_in[1];
    const float* W_kqv_user = (const float*)d_in[2];
    const float* b_kqv_user = (const float*)d_in[3];
    const float* W_kqv_item = (const float*)d_in[4];
    const float* b_kqv_item = (const float*)d_in[5];
    const float* Wk_rel     = (const float*)d_in[6];
    const float* Wv_rel     = (const float*)d_in[7];
    const float* W_out_user = (const float*)d_in[8];
    const float* b_out_user = (const float*)d_in[9];
    const float* W_out_item = (const float*)d_in[10];
    const float* b_out_item = (const float*)d_in[11];
    const float* skip_user  = (const float*)d_in[12];
    const float* skip_item  = (const float*)d_in[13];
    const float* p_ui       = (const float*)d_in[14];
    const float* p_iu       = (const float*)d_in[15];
    const int*   edge_ui    = (const int*)d_in[16];
    const int*   edge_iu    = (const int*)d_in[17];

    const size_t NODE_F = (size_t)NN * FDIM;     // 12.8M elems
    char* w = (char*)d_ws;
    size_t off = 0;
    auto alloc = [&](size_t bytes) {
        char* p = w + off;
        off += (bytes + 255) & ~(size_t)255;
        return p;
    };
    unsigned short* q_b   = (unsigned short*)alloc(NODE_F * 2);
    unsigned short* kk_b  = (unsigned short*)alloc(NODE_F * 2);
    unsigned short* vv_b  = (unsigned short*)alloc(NODE_F * 2);
    unsigned short* oa_b  = (unsigned short*)alloc(NODE_F * 2);
    int* esrc   = (int*)alloc((size_t)E_TOT * 4);
    int* cnt    = (int*)alloc((size_t)NN * 4);
    int* base   = (int*)alloc((size_t)NN * 4);
    int* cursor = (int*)alloc((size_t)NN * 4);
    int* bsum   = (int*)alloc((size_t)SCAN_NB * 4);
    int2* meta2 = (int2*)alloc((size_t)NN * 8);
    unsigned short* F_u    = (unsigned short*)alloc(384 * 128 * 2);
    unsigned short* F_i    = (unsigned short*)alloc(384 * 128 * 2);
    float*          bias_u = (float*)alloc(384 * 4);
    float*          bias_i = (float*)alloc(384 * 4);
    unsigned short* Fo_u   = (unsigned short*)alloc(128 * 128 * 2);
    unsigned short* Fo_i   = (unsigned short*)alloc(128 * 128 * 2);

    // weight prep (fused launches, frag layout)
    prep_kqv<<<768, 128, 0, stream>>>(W_kqv_user, b_kqv_user, W_kqv_item, b_kqv_item,
                                      Wk_rel, Wv_rel, F_u, bias_u, F_i, bias_i);
    prep_wo<<<128, 256, 0, stream>>>(W_out_user, Fo_u, W_out_item, Fo_i);

    // fused KQV(+rel) GEMM, both sides, LDS-free
    kqv_mfma<<<2 * KQV_NB, 256, 0, stream>>>(x_user, F_u, bias_u,
                                             x_item, F_i, bias_i,
                                             kk_b, q_b, vv_b);

    // CSR build
    hipMemsetAsync(cnt, 0, (size_t)NN * 4, stream);
    hist_kernel<<<(E_TOT + 255) / 256, 256, 0, stream>>>(edge_ui, edge_iu, cnt);
    scan1_kernel<<<SCAN_NB, 256, 0, stream>>>(cnt, base, bsum);
    scan3_kernel<<<(NN + 255) / 256, 256, 0, stream>>>(base, bsum, cnt, cursor, meta2);
    fill_kernel<<<(E_TOT + 255) / 256, 256, 0, stream>>>(edge_ui, edge_iu, cursor, esrc);

    attn_fused<<<2048, 256, 0, stream>>>(q_b, kk_b, vv_b, meta2, esrc,
                                         p_ui, p_iu, oa_b);

    // final GEMM, both sides, LDS-free (gelu already applied in attn)
    final_mfma<<<2 * KQV_NB, 256, 0, stream>>>(
        oa_b, x_user, Fo_u, b_out_user, skip_user,
        x_item, Fo_i, b_out_item, skip_item, (float*)d_out);
}

// Round 12
// 242.095 us; speedup vs baseline: 1.0330x; 1.0330x over previous
//
#include <hip/hip_runtime.h>
#include <hip/hip_bf16.h>
#include <math.h>

#define N_USERS 50000
#define N_ITEMS 50000
#define NN      100000
#define E_PER_  400000
#define E_TOT   800000
#define FDIM    128
#define NH      4
#define HD      32
#define SCAN_CHUNK 1024
#define SCAN_NB    ((NN + SCAN_CHUNK - 1) / SCAN_CHUNK)   // 98
#define KQV_NB  ((N_USERS + 127) / 128)                   // 391 per side

typedef __attribute__((ext_vector_type(8))) short bfrag;   // 8 bf16 (4 VGPR)
typedef __attribute__((ext_vector_type(4))) float f32x4;

__device__ __forceinline__ float gelu_exact(float x) {
    return 0.5f * x * (1.0f + erff(x * 0.70710678118654752f));
}
__device__ __forceinline__ unsigned short f2bf(float f) {
    unsigned u = __float_as_uint(f);
    unsigned r = u + 0x7fffu + ((u >> 16) & 1u);
    return (unsigned short)(r >> 16);
}
__device__ __forceinline__ void unpack8(uint4 u, float* f) {
    f[0] = __uint_as_float(u.x << 16); f[1] = __uint_as_float(u.x & 0xffff0000u);
    f[2] = __uint_as_float(u.y << 16); f[3] = __uint_as_float(u.y & 0xffff0000u);
    f[4] = __uint_as_float(u.z << 16); f[5] = __uint_as_float(u.z & 0xffff0000u);
    f[6] = __uint_as_float(u.w << 16); f[7] = __uint_as_float(u.w & 0xffff0000u);
}
// fragment slot index for A-operand W (16B per lane): n = matrix row, k = contraction
__device__ __forceinline__ size_t wfrag_idx(int n, int k) {
    int ch = n >> 7, nt = (n >> 4) & 7, lr = n & 15;
    int ks = k >> 5, lg = (k >> 3) & 3, e = k & 7;
    return ((size_t)(((ch * 8 + nt) * 4 + ks) * 64 + lg * 16 + lr)) * 8 + e;
}

// ---------------------------------------------------------------------------
// Weight prep: fuse rel-transform into KQV weights; emit in MFMA frag layout.
// ---------------------------------------------------------------------------
__global__ void prep_kqv(
    const float* __restrict__ W_u, const float* __restrict__ b_u,
    const float* __restrict__ W_i, const float* __restrict__ b_i,
    const float* __restrict__ Wk_rel, const float* __restrict__ Wv_rel,
    unsigned short* __restrict__ F_u, float* __restrict__ bias_u,
    unsigned short* __restrict__ F_i, float* __restrict__ bias_i)
{
    const int et = blockIdx.x >= 384;
    const int n = blockIdx.x - et * 384;   // 0..383
    const int k = threadIdx.x;             // 0..127
    const float* W = et ? W_i : W_u;
    const float* b = et ? b_i : b_u;
    unsigned short* F = et ? F_i : F_u;
    float* bias_f = et ? bias_i : bias_u;
    float s;
    if (n < 128) {
        int h = n >> 5, e = n & 31;
        const float* wr = Wk_rel + (size_t)(h * 2 + et) * 1024 + e;
        const float* wc = W + (size_t)k * 384 + h * 32;
        s = 0.f;
        for (int d = 0; d < 32; ++d) s = fmaf(wc[d], wr[d * 32], s);
        if (k == 0) {
            float bs = 0.f;
            for (int d = 0; d < 32; ++d) bs = fmaf(b[h * 32 + d], wr[d * 32], bs);
            bias_f[n] = bs;
        }
    } else if (n < 256) {
        s = W[(size_t)k * 384 + n];
        if (k == 0) bias_f[n] = b[n];
    } else {
        int h = (n - 256) >> 5, e = (n - 256) & 31;
        const float* wr = Wv_rel + (size_t)(h * 2 + et) * 1024 + e;
        const float* wc = W + (size_t)k * 384 + 256 + h * 32;
        s = 0.f;
        for (int d = 0; d < 32; ++d) s = fmaf(wc[d], wr[d * 32], s);
        if (k == 0) {
            float bs = 0.f;
            for (int d = 0; d < 32; ++d) bs = fmaf(b[256 + h * 32 + d], wr[d * 32], bs);
            bias_f[n] = bs;
        }
    }
    F[wfrag_idx(n, k)] = f2bf(s);
}

// W_out[k][n] f32 -> frag layout bf16 (single 128-chunk)
__global__ void prep_wo(
    const float* __restrict__ W_u, unsigned short* __restrict__ F_u,
    const float* __restrict__ W_i, unsigned short* __restrict__ F_i)
{
    int i = blockIdx.x * blockDim.x + threadIdx.x;   // 0..2*16384
    int side = i >= 128 * 128;
    int j = i - side * 128 * 128;
    if (j >= 128 * 128) return;
    int n = j >> 7, k = j & 127;
    const float* W = side ? W_i : W_u;
    unsigned short* F = side ? F_i : F_u;
    F[wfrag_idx(n, k)] = f2bf(W[(size_t)k * 128 + n]);
}

// ---------------------------------------------------------------------------
// KQV GEMM, LDS-free. BM=128 (4 waves x 32 rows), N=384 in 3 chunks.
// ---------------------------------------------------------------------------
__global__ __launch_bounds__(256, 3) void kqv_mfma(
    const float* __restrict__ X_u, const unsigned short* __restrict__ F_u,
    const float* __restrict__ bias_u,
    const float* __restrict__ X_i, const unsigned short* __restrict__ F_i,
    const float* __restrict__ bias_i,
    unsigned short* __restrict__ kk_b,
    unsigned short* __restrict__ q_b,
    unsigned short* __restrict__ vv_b)
{
    const int t = threadIdx.x;
    const int side = blockIdx.x >= KQV_NB;
    const int m0 = (blockIdx.x - side * KQV_NB) * 128;
    const float* X = side ? X_i : X_u;
    const unsigned short* F = side ? F_i : F_u;
    const float* bias = side ? bias_i : bias_u;
    const int side_off = side ? N_USERS : 0;
    const int M = N_USERS;

    const int wave = t >> 6, lane = t & 63;
    const int lr = lane & 15, lg = lane >> 4;
    const int rbase = m0 + wave * 32;

    bfrag am[2][4];
    #pragma unroll
    for (int mt = 0; mt < 2; ++mt)
        #pragma unroll
        for (int ks = 0; ks < 4; ++ks) {
            int row = rbase + mt * 16 + lr;
            float4 a = make_float4(0.f, 0.f, 0.f, 0.f);
            float4 b4 = make_float4(0.f, 0.f, 0.f, 0.f);
            if (row < M) {
                const float* px = X + (size_t)row * 128 + ks * 32 + lg * 8;
                a  = *reinterpret_cast<const float4*>(px);
                b4 = *reinterpret_cast<const float4*>(px + 4);
            }
            uint4 pk;
            pk.x = (unsigned)f2bf(a.x)  | ((unsigned)f2bf(a.y)  << 16);
            pk.y = (unsigned)f2bf(a.z)  | ((unsigned)f2bf(a.w)  << 16);
            pk.z = (unsigned)f2bf(b4.x) | ((unsigned)f2bf(b4.y) << 16);
            pk.w = (unsigned)f2bf(b4.z) | ((unsigned)f2bf(b4.w) << 16);
            am[mt][ks] = *reinterpret_cast<bfrag*>(&pk);
        }

    #pragma unroll
    for (int ch = 0; ch < 3; ++ch) {
        f32x4 acc[2][8];
        const f32x4 zero = {0.f, 0.f, 0.f, 0.f};
        #pragma unroll
        for (int mt = 0; mt < 2; ++mt)
            #pragma unroll
            for (int nt = 0; nt < 8; ++nt) acc[mt][nt] = zero;

        bfrag bc[4], bn[4];
        #pragma unroll
        for (int ks = 0; ks < 4; ++ks)
            bc[ks] = *reinterpret_cast<const bfrag*>(
                F + ((size_t)((ch * 8 + 0) * 4 + ks) * 64 + lane) * 8);

        #pragma unroll
        for (int nt = 0; nt < 8; ++nt) {
            if (nt < 7) {
                #pragma unroll
                for (int ks = 0; ks < 4; ++ks)
                    bn[ks] = *reinterpret_cast<const bfrag*>(
                        F + ((size_t)((ch * 8 + nt + 1) * 4 + ks) * 64 + lane) * 8);
            }
            #pragma unroll
            for (int mt = 0; mt < 2; ++mt)
                #pragma unroll
                for (int ks = 0; ks < 4; ++ks)
                    acc[mt][nt] = __builtin_amdgcn_mfma_f32_16x16x32_bf16(
                        bc[ks], am[mt][ks], acc[mt][nt], 0, 0, 0);
            #pragma unroll
            for (int ks = 0; ks < 4; ++ks) bc[ks] = bn[ks];
        }

        unsigned short* arr = (ch == 0) ? kk_b : (ch == 1) ? q_b : vv_b;
        #pragma unroll
        for (int nt = 0; nt < 8; ++nt) {
            float4 bv = *reinterpret_cast<const float4*>(bias + ch * 128 + nt * 16 + lg * 4);
            #pragma unroll
            for (int mt = 0; mt < 2; ++mt) {
                int row = rbase + mt * 16 + lr;
                if (row < M) {
                    unsigned lo = (unsigned)f2bf(acc[mt][nt][0] + bv.x)
                                | ((unsigned)f2bf(acc[mt][nt][1] + bv.y) << 16);
                    unsigned hi = (unsigned)f2bf(acc[mt][nt][2] + bv.z)
                                | ((unsigned)f2bf(acc[mt][nt][3] + bv.w) << 16);
                    uint2 st = make_uint2(lo, hi);
                    *reinterpret_cast<uint2*>(
                        arr + (size_t)(side_off + row) * 128 + nt * 16 + lg * 4) = st;
                }
            }
        }
    }
}

// ---------------------------------------------------------------------------
// CSR build: histogram -> scan1 -> scan3(inline bsum prefix, emits int2 meta)
// -> fill
// ---------------------------------------------------------------------------
__device__ __forceinline__ void edge_src_dst(
    int e, const int* __restrict__ edge_ui, const int* __restrict__ edge_iu,
    int& src, int& dst)
{
    if (e < E_PER_) {
        src = edge_ui[e];
        dst = edge_ui[E_PER_ + e] + N_USERS;
    } else {
        int e2 = e - E_PER_;
        src = N_USERS + edge_iu[e2];
        dst = edge_iu[E_PER_ + e2];
    }
}

__global__ __launch_bounds__(256) void hist_kernel(
    const int* __restrict__ edge_ui, const int* __restrict__ edge_iu,
    int* __restrict__ cnt)
{
    int e = blockIdx.x * blockDim.x + threadIdx.x;
    if (e >= E_TOT) return;
    int src, dst;
    edge_src_dst(e, edge_ui, edge_iu, src, dst);
    atomicAdd(cnt + dst, 1);
}

__global__ __launch_bounds__(256) void scan1_kernel(
    const int* __restrict__ cnt, int* __restrict__ base, int* __restrict__ bsum)
{
    __shared__ int ssum[256];
    const int t = threadIdx.x;
    const int i0 = blockIdx.x * SCAN_CHUNK + t * 4;
    int v[4];
    #pragma unroll
    for (int j = 0; j < 4; ++j) v[j] = (i0 + j < NN) ? cnt[i0 + j] : 0;
    int tsum = v[0] + v[1] + v[2] + v[3];
    ssum[t] = tsum;
    __syncthreads();
    int run = tsum;
    for (int off = 1; off < 256; off <<= 1) {
        int o = (t >= off) ? ssum[t - off] : 0;
        __syncthreads();
        run += o;
        ssum[t] = run;
        __syncthreads();
    }
    int excl = run - tsum;
    int p = excl;
    #pragma unroll
    for (int j = 0; j < 4; ++j) {
        if (i0 + j < NN) base[i0 + j] = p;
        p += v[j];
    }
    if (t == 255) bsum[blockIdx.x] = run;
}

// scan3: adds chunk-prefix of bsum; writes cursor and packed (base,cnt) meta.
__global__ __launch_bounds__(256) void scan3_kernel(
    const int* __restrict__ base, const int* __restrict__ bsum,
    const int* __restrict__ cnt,
    int* __restrict__ cursor, int2* __restrict__ meta2)
{
    const int lane = threadIdx.x & 63;
    const int chunk = blockIdx.x >> 2;          // 256 threads, 1024-chunks
    int v0 = (lane < chunk) ? bsum[lane] : 0;
    int v1 = (64 + lane < chunk && 64 + lane < SCAN_NB) ? bsum[64 + lane] : 0;
    int s = v0 + v1;
    #pragma unroll
    for (int off = 1; off < 64; off <<= 1) s += __shfl_xor(s, off);
    int i = blockIdx.x * 256 + threadIdx.x;
    if (i < NN) {
        int b = base[i] + s;
        cursor[i] = b;
        meta2[i] = make_int2(b, cnt[i]);
    }
}

__global__ __launch_bounds__(256) void fill_kernel(
    const int* __restrict__ edge_ui, const int* __restrict__ edge_iu,
    int* __restrict__ cursor, int* __restrict__ esrc)
{
    int e = blockIdx.x * blockDim.x + threadIdx.x;
    if (e >= E_TOT) return;
    int src, dst;
    edge_src_dst(e, edge_ui, edge_iu, src, dst);
    int pos = atomicAdd(cursor + dst, 1);
    esrc[pos] = src;
}

// ---------------------------------------------------------------------------
// Fused attention v6: wave/node, FOUR edges/iter (g=lane>>4, p=lane&15 ->
// dims 8p..8p+7, head h=p>>2), intra-node prefetch (R5 structure, 75% VALU),
// direct exp, epilogue = 2-level reduce-scatter -> every lane owns 2 dims
// -> 2 gelus/lane on ALL lanes, 4B store.
// ---------------------------------------------------------------------------
__global__ __launch_bounds__(256) void attn_fused(
    const unsigned short* __restrict__ q_b, const unsigned short* __restrict__ kk_b,
    const unsigned short* __restrict__ vv_b,
    const int2* __restrict__ meta2, const int* __restrict__ esrc,
    const float* __restrict__ p_ui, const float* __restrict__ p_iu,
    unsigned short* __restrict__ oa)
{
    const int wid  = (blockIdx.x * blockDim.x + threadIdx.x) >> 6;
    const int lane = threadIdx.x & 63;
    const int nw   = (gridDim.x * blockDim.x) >> 6;
    const int g    = lane >> 4;      // edge slot 0..3
    const int p    = lane & 15;      // dims 8p..8p+7
    const int h    = p >> 2;         // head
    const float rsd = 0.17677669529663687f;   // 1/sqrt(32)
    const float pu = p_ui[h], pi = p_iu[h];

    for (int n = wid; n < NN; n += nw) {
        const float pr = (n >= N_USERS) ? pu : pi;
        float qf[8];
        unpack8(*reinterpret_cast<const uint4*>(q_b + (size_t)n * 128 + p * 8), qf);
        float l = 0.f;
        float acc[8] = {0.f, 0.f, 0.f, 0.f, 0.f, 0.f, 0.f, 0.f};
        const int2 mt = meta2[n];
        const int s0 = mt.x, c = mt.y;

        if (c > 0) {
            bool valid = g < c;
            int src = esrc[s0 + (valid ? g : 0)];
            uint4 k4 = *reinterpret_cast<const uint4*>(kk_b + (size_t)src * 128 + p * 8);
            uint4 v4 = *reinterpret_cast<const uint4*>(vv_b + (size_t)src * 128 + p * 8);

            for (int j = 0; j < c; j += 4) {
                uint4 k4n, v4n;
                bool validn = false;
                if (j + 4 < c) {
                    int jn = j + 4 + g;
                    validn = jn < c;
                    int srcn = esrc[s0 + (validn ? jn : 0)];
                    k4n = *reinterpret_cast<const uint4*>(kk_b + (size_t)srcn * 128 + p * 8);
                    v4n = *reinterpret_cast<const uint4*>(vv_b + (size_t)srcn * 128 + p * 8);
                }

                float kf[8];
                unpack8(k4, kf);
                float s = qf[0] * kf[0];
                #pragma unroll
                for (int i = 1; i < 8; ++i) s = fmaf(qf[i], kf[i], s);
                s += __shfl_xor(s, 1);
                s += __shfl_xor(s, 2);       // head = 4 lanes x 8 dims
                float w = valid ? __expf(s * pr * rsd) : 0.f;
                l += w;
                float vf[8];
                unpack8(v4, vf);
                #pragma unroll
                for (int i = 0; i < 8; ++i) acc[i] = fmaf(w, vf[i], acc[i]);

                k4 = k4n; v4 = v4n; valid = validn;
            }
        }

        // per-head denominator: sum over the 4 edge groups (lane bits 4,5)
        l += __shfl_xor(l, 16); l += __shfl_xor(l, 32);

        // reduce-scatter acc[8] across the 4 groups (2 levels, static indices)
        const bool b1 = (g & 2) != 0;   // lane bit 5
        float k4r[4];
        #pragma unroll
        for (int i = 0; i < 4; ++i) {
            float mine = b1 ? acc[4 + i] : acc[i];
            float send = b1 ? acc[i] : acc[4 + i];
            k4r[i] = mine + __shfl_xor(send, 32);
        }
        const bool b0 = (g & 1) != 0;   // lane bit 4
        float k2[2];
        #pragma unroll
        for (int i = 0; i < 2; ++i) {
            float mine = b0 ? k4r[2 + i] : k4r[i];
            float send = b0 ? k4r[i] : k4r[2 + i];
            k2[i] = mine + __shfl_xor(send, 16);
        }
        // lane (g,p) owns dims 8p + 2g, 8p + 2g + 1
        float inv = 1.0f / (l + 1e-16f);
        unsigned pk = (unsigned)f2bf(gelu_exact(k2[0] * inv))
                    | ((unsigned)f2bf(gelu_exact(k2[1] * inv)) << 16);
        *reinterpret_cast<unsigned*>(oa + (size_t)n * 128 + p * 8 + 2 * g) = pk;
    }
}

// ---------------------------------------------------------------------------
// Final GEMM, LDS-free (both sides): out = sg*(oa_gelu @ Wo + bo) + (1-sg)*x.
// R6 structure: dbuf weight frags, (256,3), no gelu (done in attn).
// ---------------------------------------------------------------------------
__global__ __launch_bounds__(256, 3) void final_mfma(
    const unsigned short* __restrict__ oa,   // [NN][128] bf16, gelu'd
    const float* __restrict__ x_u, const unsigned short* __restrict__ F_u,
    const float* __restrict__ bo_u, const float* __restrict__ skip_u,
    const float* __restrict__ x_i, const unsigned short* __restrict__ F_i,
    const float* __restrict__ bo_i, const float* __restrict__ skip_i,
    float* __restrict__ out)
{
    const int t = threadIdx.x;
    const int side = blockIdx.x >= KQV_NB;
    const int m0 = (blockIdx.x - side * KQV_NB) * 128;
    const float* x = side ? x_i : x_u;
    const unsigned short* F = side ? F_i : F_u;
    const float* bo = side ? bo_i : bo_u;
    const float* skip = side ? skip_i : skip_u;
    const int row_off = side ? N_USERS : 0;
    const int M = N_USERS;

    const int wave = t >> 6, lane = t & 63;
    const int lr = lane & 15, lg = lane >> 4;
    const int rbase = m0 + wave * 32;

    bfrag am[2][4];
    const bfrag bz = {0, 0, 0, 0, 0, 0, 0, 0};
    #pragma unroll
    for (int mt = 0; mt < 2; ++mt)
        #pragma unroll
        for (int ks = 0; ks < 4; ++ks) {
            int row = rbase + mt * 16 + lr;
            am[mt][ks] = (row < M)
                ? *reinterpret_cast<const bfrag*>(
                      oa + (size_t)(row_off + row) * 128 + ks * 32 + lg * 8)
                : bz;
        }

    f32x4 acc[2][8];
    const f32x4 zero = {0.f, 0.f, 0.f, 0.f};
    #pragma unroll
    for (int mt = 0; mt < 2; ++mt)
        #pragma unroll
        for (int nt = 0; nt < 8; ++nt) acc[mt][nt] = zero;

    bfrag bc[4], bn[4];
    #pragma unroll
    for (int ks = 0; ks < 4; ++ks)
        bc[ks] = *reinterpret_cast<const bfrag*>(
            F + ((size_t)(0 * 4 + ks) * 64 + lane) * 8);

    #pragma unroll
    for (int nt = 0; nt < 8; ++nt) {
        if (nt < 7) {
            #pragma unroll
            for (int ks = 0; ks < 4; ++ks)
                bn[ks] = *reinterpret_cast<const bfrag*>(
                    F + ((size_t)((nt + 1) * 4 + ks) * 64 + lane) * 8);
        }
        #pragma unroll
        for (int mt = 0; mt < 2; ++mt)
            #pragma unroll
            for (int ks = 0; ks < 4; ++ks)
                acc[mt][nt] = __builtin_amdgcn_mfma_f32_16x16x32_bf16(
                    bc[ks], am[mt][ks], acc[mt][nt], 0, 0, 0);
        #pragma unroll
        for (int ks = 0; ks < 4; ++ks) bc[ks] = bn[ks];
    }

    const float sg = 1.0f / (1.0f + expf(-skip[0]));
    #pragma unroll
    for (int nt = 0; nt < 8; ++nt) {
        float4 bv = *reinterpret_cast<const float4*>(bo + nt * 16 + lg * 4);
        #pragma unroll
        for (int mt = 0; mt < 2; ++mt) {
            int row = rbase + mt * 16 + lr;
            if (row < M) {
                float4 xv = *reinterpret_cast<const float4*>(
                    x + (size_t)row * 128 + nt * 16 + lg * 4);
                float4 res;
                res.x = sg * (acc[mt][nt][0] + bv.x) + (1.f - sg) * xv.x;
                res.y = sg * (acc[mt][nt][1] + bv.y) + (1.f - sg) * xv.y;
                res.z = sg * (acc[mt][nt][2] + bv.z) + (1.f - sg) * xv.z;
                res.w = sg * (acc[mt][nt][3] + bv.w) + (1.f - sg) * xv.w;
                *reinterpret_cast<float4*>(
                    out + (size_t)(row_off + row) * 128 + nt * 16 + lg * 4) = res;
            }
        }
    }
}

// ---------------------------------------------------------------------------
extern "C" void kernel_launch(void* const* d_in, const int* in_sizes, int n_in,
                              void* d_out, int out_size, void* d_ws, size_t ws_size,
                              hipStream_t stream)
{
    const float* x_user     = (const float*)d_in[0];
    const float* x_item     = (const float*)d_in[1];
    const float* W_kqv_user = (const float*)d_in[2];
    const float* b_kqv_user = (const float*)d_in[3];
    const float* W_kqv_item = (const float*)d_in[4];
    const float* b_kqv_item = (const float*)d_in[5];
    const float* Wk_rel     = (const float*)d_in[6];
    const float* Wv_rel     = (const float*)d_in[7];
    const float* W_out_user = (const float*)d_in[8];
    const float* b_out_user = (const float*)d_in[9];
    const float* W_out_item = (const float*)d_in[10];
    const float* b_out_item = (const float*)d_in[11];
    const float* skip_user  = (const float*)d_in[12];
    const float* skip_item  = (const float*)d_in[13];
    const float* p_ui       = (const float*)d_in[14];
    const float* p_iu       = (const float*)d_in[15];
    const int*   edge_ui    = (const int*)d_in[16];
    const int*   edge_iu    = (const int*)d_in[17];

    const size_t NODE_F = (size_t)NN * FDIM;     // 12.8M elems
    char* w = (char*)d_ws;
    size_t off = 0;
    auto alloc = [&](size_t bytes) {
        char* p = w + off;
        off += (bytes + 255) & ~(size_t)255;
        return p;
    };
    unsigned short* q_b   = (unsigned short*)alloc(NODE_F * 2);
    unsigned short* kk_b  = (unsigned short*)alloc(NODE_F * 2);
    unsigned short* vv_b  = (unsigned short*)alloc(NODE_F * 2);
    unsigned short* oa_b  = (unsigned short*)alloc(NODE_F * 2);
    int* esrc   = (int*)alloc((size_t)E_TOT * 4);
    int* cnt    = (int*)alloc((size_t)NN * 4);
    int* base   = (int*)alloc((size_t)NN * 4);
    int* cursor = (int*)alloc((size_t)NN * 4);
    int* bsum   = (int*)alloc((size_t)SCAN_NB * 4);
    int2* meta2 = (int2*)alloc((size_t)NN * 8);
    unsigned short* F_u    = (unsigned short*)alloc(384 * 128 * 2);
    unsigned short* F_i    = (unsigned short*)alloc(384 * 128 * 2);
    float*          bias_u = (float*)alloc(384 * 4);
    float*          bias_i = (float*)alloc(384 * 4);
    unsigned short* Fo_u   = (unsigned short*)alloc(128 * 128 * 2);
    unsigned short* Fo_i   = (unsigned short*)alloc(128 * 128 * 2);

    // weight prep (fused launches, frag layout)
    prep_kqv<<<768, 128, 0, stream>>>(W_kqv_user, b_kqv_user, W_kqv_item, b_kqv_item,
                                      Wk_rel, Wv_rel, F_u, bias_u, F_i, bias_i);
    prep_wo<<<128, 256, 0, stream>>>(W_out_user, Fo_u, W_out_item, Fo_i);

    // fused KQV(+rel) GEMM, both sides, LDS-free
    kqv_mfma<<<2 * KQV_NB, 256, 0, stream>>>(x_user, F_u, bias_u,
                                             x_item, F_i, bias_i,
                                             kk_b, q_b, vv_b);

    // CSR build
    hipMemsetAsync(cnt, 0, (size_t)NN * 4, stream);
    hist_kernel<<<(E_TOT + 255) / 256, 256, 0, stream>>>(edge_ui, edge_iu, cnt);
    scan1_kernel<<<SCAN_NB, 256, 0, stream>>>(cnt, base, bsum);
    scan3_kernel<<<(NN + 255) / 256, 256, 0, stream>>>(base, bsum, cnt, cursor, meta2);
    fill_kernel<<<(E_TOT + 255) / 256, 256, 0, stream>>>(edge_ui, edge_iu, cursor, esrc);

    attn_fused<<<2048, 256, 0, stream>>>(q_b, kk_b, vv_b, meta2, esrc,
                                         p_ui, p_iu, oa_b);

    // final GEMM, both sides, LDS-free (gelu already applied in attn)
    final_mfma<<<2 * KQV_NB, 256, 0, stream>>>(
        oa_b, x_user, Fo_u, b_out_user, skip_user,
        x_item, Fo_i, b_out_item, skip_item, (float*)d_out);
}

// Round 14
// 235.980 us; speedup vs baseline: 1.0598x; 1.0259x over previous
//
#include <hip/hip_runtime.h>
#include <hip/hip_bf16.h>
#include <math.h>

#define N_USERS 50000
#define N_ITEMS 50000
#define NN      100000
#define E_PER_  400000
#define E_TOT   800000
#define FDIM    128
#define NH      4
#define HD      32
#define SCAN_CHUNK 1024
#define SCAN_NB    ((NN + SCAN_CHUNK - 1) / SCAN_CHUNK)   // 98
#define KQV_NB  ((N_USERS + 127) / 128)                   // 391 per side

typedef _Float16 h2 __attribute__((ext_vector_type(2)));
typedef _Float16 h8 __attribute__((ext_vector_type(8)));   // mfma f16 operand frag
typedef __attribute__((ext_vector_type(4))) float f32x4;

__device__ __forceinline__ float gelu_exact(float x) {
    return 0.5f * x * (1.0f + erff(x * 0.70710678118654752f));
}
__device__ __forceinline__ unsigned short f2h_bits(float f) {
    _Float16 h = (_Float16)f;
    union { _Float16 h; unsigned short u; } c; c.h = h; return c.u;
}
// cvt_pkrtz returns __fp16x2; bit_cast to our _Float16-based h2 (R13 fix)
__device__ __forceinline__ h2 pkrtz(float a, float b) {
    return __builtin_bit_cast(h2, __builtin_amdgcn_cvt_pkrtz(a, b));
}
__device__ __forceinline__ unsigned h2_as_u(h2 x) {
    union { h2 h; unsigned u; } c; c.h = x; return c.u;
}
__device__ __forceinline__ h2 u_as_h2(unsigned x) {
    union { h2 h; unsigned u; } c; c.u = x; return c.h;
}
__device__ __forceinline__ h2 shfl_h2(h2 x, int m) {
    return u_as_h2((unsigned)__shfl_xor((int)h2_as_u(x), m));
}
// fragment slot index for A-operand W (16B per lane): n = matrix row, k = contraction
__device__ __forceinline__ size_t wfrag_idx(int n, int k) {
    int ch = n >> 7, nt = (n >> 4) & 7, lr = n & 15;
    int ks = k >> 5, lg = (k >> 3) & 3, e = k & 7;
    return ((size_t)(((ch * 8 + nt) * 4 + ks) * 64 + lg * 16 + lr)) * 8 + e;
}

// ---------------------------------------------------------------------------
// Weight prep: fuse rel-transform into KQV weights; emit f16 in frag layout.
// ---------------------------------------------------------------------------
__global__ void prep_kqv(
    const float* __restrict__ W_u, const float* __restrict__ b_u,
    const float* __restrict__ W_i, const float* __restrict__ b_i,
    const float* __restrict__ Wk_rel, const float* __restrict__ Wv_rel,
    unsigned short* __restrict__ F_u, float* __restrict__ bias_u,
    unsigned short* __restrict__ F_i, float* __restrict__ bias_i)
{
    const int et = blockIdx.x >= 384;
    const int n = blockIdx.x - et * 384;   // 0..383
    const int k = threadIdx.x;             // 0..127
    const float* W = et ? W_i : W_u;
    const float* b = et ? b_i : b_u;
    unsigned short* F = et ? F_i : F_u;
    float* bias_f = et ? bias_i : bias_u;
    float s;
    if (n < 128) {
        int h = n >> 5, e = n & 31;
        const float* wr = Wk_rel + (size_t)(h * 2 + et) * 1024 + e;
        const float* wc = W + (size_t)k * 384 + h * 32;
        s = 0.f;
        for (int d = 0; d < 32; ++d) s = fmaf(wc[d], wr[d * 32], s);
        if (k == 0) {
            float bs = 0.f;
            for (int d = 0; d < 32; ++d) bs = fmaf(b[h * 32 + d], wr[d * 32], bs);
            bias_f[n] = bs;
        }
    } else if (n < 256) {
        s = W[(size_t)k * 384 + n];
        if (k == 0) bias_f[n] = b[n];
    } else {
        int h = (n - 256) >> 5, e = (n - 256) & 31;
        const float* wr = Wv_rel + (size_t)(h * 2 + et) * 1024 + e;
        const float* wc = W + (size_t)k * 384 + 256 + h * 32;
        s = 0.f;
        for (int d = 0; d < 32; ++d) s = fmaf(wc[d], wr[d * 32], s);
        if (k == 0) {
            float bs = 0.f;
            for (int d = 0; d < 32; ++d) bs = fmaf(b[256 + h * 32 + d], wr[d * 32], bs);
            bias_f[n] = bs;
        }
    }
    F[wfrag_idx(n, k)] = f2h_bits(s);
}

// W_out[k][n] f32 -> frag layout f16 (single 128-chunk)
__global__ void prep_wo(
    const float* __restrict__ W_u, unsigned short* __restrict__ F_u,
    const float* __restrict__ W_i, unsigned short* __restrict__ F_i)
{
    int i = blockIdx.x * blockDim.x + threadIdx.x;   // 0..2*16384
    int side = i >= 128 * 128;
    int j = i - side * 128 * 128;
    if (j >= 128 * 128) return;
    int n = j >> 7, k = j & 127;
    const float* W = side ? W_i : W_u;
    unsigned short* F = side ? F_i : F_u;
    F[wfrag_idx(n, k)] = f2h_bits(W[(size_t)k * 128 + n]);
}

// ---------------------------------------------------------------------------
// KQV GEMM, LDS-free, f16 MFMA. BM=128 (4 waves x 32 rows), N=384, 3 chunks.
// ---------------------------------------------------------------------------
__global__ __launch_bounds__(256, 3) void kqv_mfma(
    const float* __restrict__ X_u, const unsigned short* __restrict__ F_u,
    const float* __restrict__ bias_u,
    const float* __restrict__ X_i, const unsigned short* __restrict__ F_i,
    const float* __restrict__ bias_i,
    unsigned short* __restrict__ kk_b,
    unsigned short* __restrict__ q_b,
    unsigned short* __restrict__ vv_b)
{
    const int t = threadIdx.x;
    const int side = blockIdx.x >= KQV_NB;
    const int m0 = (blockIdx.x - side * KQV_NB) * 128;
    const float* X = side ? X_i : X_u;
    const unsigned short* F = side ? F_i : F_u;
    const float* bias = side ? bias_i : bias_u;
    const int side_off = side ? N_USERS : 0;
    const int M = N_USERS;

    const int wave = t >> 6, lane = t & 63;
    const int lr = lane & 15, lg = lane >> 4;
    const int rbase = m0 + wave * 32;

    h8 am[2][4];
    #pragma unroll
    for (int mt = 0; mt < 2; ++mt)
        #pragma unroll
        for (int ks = 0; ks < 4; ++ks) {
            int row = rbase + mt * 16 + lr;
            float4 a = make_float4(0.f, 0.f, 0.f, 0.f);
            float4 b4 = make_float4(0.f, 0.f, 0.f, 0.f);
            if (row < M) {
                const float* px = X + (size_t)row * 128 + ks * 32 + lg * 8;
                a  = *reinterpret_cast<const float4*>(px);
                b4 = *reinterpret_cast<const float4*>(px + 4);
            }
            union { h2 q[4]; h8 f; } u;
            u.q[0] = pkrtz(a.x, a.y);
            u.q[1] = pkrtz(a.z, a.w);
            u.q[2] = pkrtz(b4.x, b4.y);
            u.q[3] = pkrtz(b4.z, b4.w);
            am[mt][ks] = u.f;
        }

    #pragma unroll
    for (int ch = 0; ch < 3; ++ch) {
        f32x4 acc[2][8];
        const f32x4 zero = {0.f, 0.f, 0.f, 0.f};
        #pragma unroll
        for (int mt = 0; mt < 2; ++mt)
            #pragma unroll
            for (int nt = 0; nt < 8; ++nt) acc[mt][nt] = zero;

        h8 bc[4], bn[4];
        #pragma unroll
        for (int ks = 0; ks < 4; ++ks)
            bc[ks] = *reinterpret_cast<const h8*>(
                F + ((size_t)((ch * 8 + 0) * 4 + ks) * 64 + lane) * 8);

        #pragma unroll
        for (int nt = 0; nt < 8; ++nt) {
            if (nt < 7) {
                #pragma unroll
                for (int ks = 0; ks < 4; ++ks)
                    bn[ks] = *reinterpret_cast<const h8*>(
                        F + ((size_t)((ch * 8 + nt + 1) * 4 + ks) * 64 + lane) * 8);
            }
            #pragma unroll
            for (int mt = 0; mt < 2; ++mt)
                #pragma unroll
                for (int ks = 0; ks < 4; ++ks)
                    acc[mt][nt] = __builtin_amdgcn_mfma_f32_16x16x32_f16(
                        bc[ks], am[mt][ks], acc[mt][nt], 0, 0, 0);
            #pragma unroll
            for (int ks = 0; ks < 4; ++ks) bc[ks] = bn[ks];
        }

        unsigned short* arr = (ch == 0) ? kk_b : (ch == 1) ? q_b : vv_b;
        #pragma unroll
        for (int nt = 0; nt < 8; ++nt) {
            float4 bv = *reinterpret_cast<const float4*>(bias + ch * 128 + nt * 16 + lg * 4);
            #pragma unroll
            for (int mt = 0; mt < 2; ++mt) {
                int row = rbase + mt * 16 + lr;
                if (row < M) {
                    h2 lo = pkrtz(acc[mt][nt][0] + bv.x, acc[mt][nt][1] + bv.y);
                    h2 hi = pkrtz(acc[mt][nt][2] + bv.z, acc[mt][nt][3] + bv.w);
                    uint2 st = make_uint2(h2_as_u(lo), h2_as_u(hi));
                    *reinterpret_cast<uint2*>(
                        arr + (size_t)(side_off + row) * 128 + nt * 16 + lg * 4) = st;
                }
            }
        }
    }
}

// ---------------------------------------------------------------------------
// CSR build: histogram -> scan1 -> scan3(inline bsum prefix, emits int2 meta)
// -> fill
// ---------------------------------------------------------------------------
__device__ __forceinline__ void edge_src_dst(
    int e, const int* __restrict__ edge_ui, const int* __restrict__ edge_iu,
    int& src, int& dst)
{
    if (e < E_PER_) {
        src = edge_ui[e];
        dst = edge_ui[E_PER_ + e] + N_USERS;
    } else {
        int e2 = e - E_PER_;
        src = N_USERS + edge_iu[e2];
        dst = edge_iu[E_PER_ + e2];
    }
}

__global__ __launch_bounds__(256) void hist_kernel(
    const int* __restrict__ edge_ui, const int* __restrict__ edge_iu,
    int* __restrict__ cnt)
{
    int e = blockIdx.x * blockDim.x + threadIdx.x;
    if (e >= E_TOT) return;
    int src, dst;
    edge_src_dst(e, edge_ui, edge_iu, src, dst);
    atomicAdd(cnt + dst, 1);
}

__global__ __launch_bounds__(256) void scan1_kernel(
    const int* __restrict__ cnt, int* __restrict__ base, int* __restrict__ bsum)
{
    __shared__ int ssum[256];
    const int t = threadIdx.x;
    const int i0 = blockIdx.x * SCAN_CHUNK + t * 4;
    int v[4];
    #pragma unroll
    for (int j = 0; j < 4; ++j) v[j] = (i0 + j < NN) ? cnt[i0 + j] : 0;
    int tsum = v[0] + v[1] + v[2] + v[3];
    ssum[t] = tsum;
    __syncthreads();
    int run = tsum;
    for (int off = 1; off < 256; off <<= 1) {
        int o = (t >= off) ? ssum[t - off] : 0;
        __syncthreads();
        run += o;
        ssum[t] = run;
        __syncthreads();
    }
    int excl = run - tsum;
    int p = excl;
    #pragma unroll
    for (int j = 0; j < 4; ++j) {
        if (i0 + j < NN) base[i0 + j] = p;
        p += v[j];
    }
    if (t == 255) bsum[blockIdx.x] = run;
}

// scan3: adds chunk-prefix of bsum; writes cursor and packed (base,cnt) meta.
__global__ __launch_bounds__(256) void scan3_kernel(
    const int* __restrict__ base, const int* __restrict__ bsum,
    const int* __restrict__ cnt,
    int* __restrict__ cursor, int2* __restrict__ meta2)
{
    const int lane = threadIdx.x & 63;
    const int chunk = blockIdx.x >> 2;          // 256 threads, 1024-chunks
    int v0 = (lane < chunk) ? bsum[lane] : 0;
    int v1 = (64 + lane < chunk && 64 + lane < SCAN_NB) ? bsum[64 + lane] : 0;
    int s = v0 + v1;
    #pragma unroll
    for (int off = 1; off < 64; off <<= 1) s += __shfl_xor(s, off);
    int i = blockIdx.x * 256 + threadIdx.x;
    if (i < NN) {
        int b = base[i] + s;
        cursor[i] = b;
        meta2[i] = make_int2(b, cnt[i]);
    }
}

__global__ __launch_bounds__(256) void fill_kernel(
    const int* __restrict__ edge_ui, const int* __restrict__ edge_iu,
    int* __restrict__ cursor, int* __restrict__ esrc)
{
    int e = blockIdx.x * blockDim.x + threadIdx.x;
    if (e >= E_TOT) return;
    int src, dst;
    edge_src_dst(e, edge_ui, edge_iu, src, dst);
    int pos = atomicAdd(cursor + dst, 1);
    esrc[pos] = src;
}

// ---------------------------------------------------------------------------
// Fused attention v7 (f16): wave/node, FOUR edges/iter (g=lane>>4, p=lane&15
// -> dims 8p..8p+7, head h=p>>2), intra-node prefetch, direct exp.
// QK dot via v_dot2_f32_f16 (no unpack), PV via packed half2 fma,
// half2 reduce-scatter, gelu on all lanes, 4B store.
// ---------------------------------------------------------------------------
__global__ __launch_bounds__(256) void attn_fused(
    const unsigned short* __restrict__ q_b, const unsigned short* __restrict__ kk_b,
    const unsigned short* __restrict__ vv_b,
    const int2* __restrict__ meta2, const int* __restrict__ esrc,
    const float* __restrict__ p_ui, const float* __restrict__ p_iu,
    unsigned short* __restrict__ oa)
{
    const int wid  = (blockIdx.x * blockDim.x + threadIdx.x) >> 6;
    const int lane = threadIdx.x & 63;
    const int nw   = (gridDim.x * blockDim.x) >> 6;
    const int g    = lane >> 4;      // edge slot 0..3
    const int p    = lane & 15;      // dims 8p..8p+7
    const int h    = p >> 2;         // head
    const float rsd = 0.17677669529663687f;   // 1/sqrt(32)
    const float pu = p_ui[h], pi = p_iu[h];

    for (int n = wid; n < NN; n += nw) {
        const float pr = (n >= N_USERS) ? pu : pi;
        union { uint4 u; h2 h[4]; } qu;
        qu.u = *reinterpret_cast<const uint4*>(q_b + (size_t)n * 128 + p * 8);
        float l = 0.f;
        h2 acc2[4];
        #pragma unroll
        for (int i = 0; i < 4; ++i) acc2[i] = (h2)(_Float16)0;
        const int2 mt = meta2[n];
        const int s0 = mt.x, c = mt.y;

        if (c > 0) {
            bool valid = g < c;
            int src = esrc[s0 + (valid ? g : 0)];
            uint4 k4 = *reinterpret_cast<const uint4*>(kk_b + (size_t)src * 128 + p * 8);
            uint4 v4 = *reinterpret_cast<const uint4*>(vv_b + (size_t)src * 128 + p * 8);

            for (int j = 0; j < c; j += 4) {
                uint4 k4n, v4n;
                bool validn = false;
                if (j + 4 < c) {
                    int jn = j + 4 + g;
                    validn = jn < c;
                    int srcn = esrc[s0 + (validn ? jn : 0)];
                    k4n = *reinterpret_cast<const uint4*>(kk_b + (size_t)srcn * 128 + p * 8);
                    v4n = *reinterpret_cast<const uint4*>(vv_b + (size_t)srcn * 128 + p * 8);
                }

                union { uint4 u; h2 h[4]; } ku, vu;
                ku.u = k4; vu.u = v4;
                float s = 0.f;
                s = __builtin_amdgcn_fdot2(qu.h[0], ku.h[0], s, false);
                s = __builtin_amdgcn_fdot2(qu.h[1], ku.h[1], s, false);
                s = __builtin_amdgcn_fdot2(qu.h[2], ku.h[2], s, false);
                s = __builtin_amdgcn_fdot2(qu.h[3], ku.h[3], s, false);
                s += __shfl_xor(s, 1);
                s += __shfl_xor(s, 2);       // head = 4 lanes x 8 dims
                float w = valid ? __expf(s * pr * rsd) : 0.f;
                l += w;
                h2 wpk = pkrtz(w, w);
                #pragma unroll
                for (int i = 0; i < 4; ++i) acc2[i] += vu.h[i] * wpk;

                k4 = k4n; v4 = v4n; valid = validn;
            }
        }

        // per-head denominator: sum over the 4 edge groups (lane bits 4,5)
        l += __shfl_xor(l, 16); l += __shfl_xor(l, 32);

        // reduce-scatter acc2[4] (8 dims) across the 4 groups, half2 adds
        const bool b1 = (g & 2) != 0;   // lane bit 5
        h2 r4[2];
        #pragma unroll
        for (int i = 0; i < 2; ++i) {
            h2 mine = b1 ? acc2[2 + i] : acc2[i];
            h2 send = b1 ? acc2[i] : acc2[2 + i];
            r4[i] = mine + shfl_h2(send, 32);
        }
        const bool b0 = (g & 1) != 0;   // lane bit 4
        h2 mine = b0 ? r4[1] : r4[0];
        h2 send = b0 ? r4[0] : r4[1];
        h2 r2 = mine + shfl_h2(send, 16);
        // lane (g,p) owns dims 8p + 2g, 8p + 2g + 1
        float inv = 1.0f / (l + 1e-16f);
        float o0 = gelu_exact((float)r2[0] * inv);
        float o1 = gelu_exact((float)r2[1] * inv);
        unsigned pk = h2_as_u(pkrtz(o0, o1));
        *reinterpret_cast<unsigned*>(oa + (size_t)n * 128 + p * 8 + 2 * g) = pk;
    }
}

// ---------------------------------------------------------------------------
// Final GEMM, LDS-free (both sides), f16 MFMA:
// out = sg*(oa_gelu @ Wo + bo) + (1-sg)*x.  dbuf weight frags, (256,3).
// ---------------------------------------------------------------------------
__global__ __launch_bounds__(256, 3) void final_mfma(
    const unsigned short* __restrict__ oa,   // [NN][128] f16, gelu'd
    const float* __restrict__ x_u, const unsigned short* __restrict__ F_u,
    const float* __restrict__ bo_u, const float* __restrict__ skip_u,
    const float* __restrict__ x_i, const unsigned short* __restrict__ F_i,
    const float* __restrict__ bo_i, const float* __restrict__ skip_i,
    float* __restrict__ out)
{
    const int t = threadIdx.x;
    const int side = blockIdx.x >= KQV_NB;
    const int m0 = (blockIdx.x - side * KQV_NB) * 128;
    const float* x = side ? x_i : x_u;
    const unsigned short* F = side ? F_i : F_u;
    const float* bo = side ? bo_i : bo_u;
    const float* skip = side ? skip_i : skip_u;
    const int row_off = side ? N_USERS : 0;
    const int M = N_USERS;

    const int wave = t >> 6, lane = t & 63;
    const int lr = lane & 15, lg = lane >> 4;
    const int rbase = m0 + wave * 32;

    h8 am[2][4];
    const h8 bz = {0, 0, 0, 0, 0, 0, 0, 0};
    #pragma unroll
    for (int mt = 0; mt < 2; ++mt)
        #pragma unroll
        for (int ks = 0; ks < 4; ++ks) {
            int row = rbase + mt * 16 + lr;
            am[mt][ks] = (row < M)
                ? *reinterpret_cast<const h8*>(
                      oa + (size_t)(row_off + row) * 128 + ks * 32 + lg * 8)
                : bz;
        }

    f32x4 acc[2][8];
    const f32x4 zero = {0.f, 0.f, 0.f, 0.f};
    #pragma unroll
    for (int mt = 0; mt < 2; ++mt)
        #pragma unroll
        for (int nt = 0; nt < 8; ++nt) acc[mt][nt] = zero;

    h8 bc[4], bn[4];
    #pragma unroll
    for (int ks = 0; ks < 4; ++ks)
        bc[ks] = *reinterpret_cast<const h8*>(
            F + ((size_t)(0 * 4 + ks) * 64 + lane) * 8);

    #pragma unroll
    for (int nt = 0; nt < 8; ++nt) {
        if (nt < 7) {
            #pragma unroll
            for (int ks = 0; ks < 4; ++ks)
                bn[ks] = *reinterpret_cast<const h8*>(
                    F + ((size_t)((nt + 1) * 4 + ks) * 64 + lane) * 8);
        }
        #pragma unroll
        for (int mt = 0; mt < 2; ++mt)
            #pragma unroll
            for (int ks = 0; ks < 4; ++ks)
                acc[mt][nt] = __builtin_amdgcn_mfma_f32_16x16x32_f16(
                    bc[ks], am[mt][ks], acc[mt][nt], 0, 0, 0);
        #pragma unroll
        for (int ks = 0; ks < 4; ++ks) bc[ks] = bn[ks];
    }

    const float sg = 1.0f / (1.0f + expf(-skip[0]));
    #pragma unroll
    for (int nt = 0; nt < 8; ++nt) {
        float4 bv = *reinterpret_cast<const float4*>(bo + nt * 16 + lg * 4);
        #pragma unroll
        for (int mt = 0; mt < 2; ++mt) {
            int row = rbase + mt * 16 + lr;
            if (row < M) {
                float4 xv = *reinterpret_cast<const float4*>(
                    x + (size_t)row * 128 + nt * 16 + lg * 4);
                float4 res;
                res.x = sg * (acc[mt][nt][0] + bv.x) + (1.f - sg) * xv.x;
                res.y = sg * (acc[mt][nt][1] + bv.y) + (1.f - sg) * xv.y;
                res.z = sg * (acc[mt][nt][2] + bv.z) + (1.f - sg) * xv.z;
                res.w = sg * (acc[mt][nt][3] + bv.w) + (1.f - sg) * xv.w;
                *reinterpret_cast<float4*>(
                    out + (size_t)(row_off + row) * 128 + nt * 16 + lg * 4) = res;
            }
        }
    }
}

// ---------------------------------------------------------------------------
extern "C" void kernel_launch(void* const* d_in, const int* in_sizes, int n_in,
                              void* d_out, int out_size, void* d_ws, size_t ws_size,
                              hipStream_t stream)
{
    const float* x_user     = (const float*)d_in[0];
    const float* x_item     = (const float*)d_in[1];
    const float* W_kqv_user = (const float*)d_in[2];
    const float* b_kqv_user = (const float*)d_in[3];
    const float* W_kqv_item = (const float*)d_in[4];
    const float* b_kqv_item = (const float*)d_in[5];
    const float* Wk_rel     = (const float*)d_in[6];
    const float* Wv_rel     = (const float*)d_in[7];
    const float* W_out_user = (const float*)d_in[8];
    const float* b_out_user = (const float*)d_in[9];
    const float* W_out_item = (const float*)d_in[10];
    const float* b_out_item = (const float*)d_in[11];
    const float* skip_user  = (const float*)d_in[12];
    const float* skip_item  = (const float*)d_in[13];
    const float* p_ui       = (const float*)d_in[14];
    const float* p_iu       = (const float*)d_in[15];
    const int*   edge_ui    = (const int*)d_in[16];
    const int*   edge_iu    = (const int*)d_in[17];

    const size_t NODE_F = (size_t)NN * FDIM;     // 12.8M elems
    char* w = (char*)d_ws;
    size_t off = 0;
    auto alloc = [&](size_t bytes) {
        char* p = w + off;
        off += (bytes + 255) & ~(size_t)255;
        return p;
    };
    unsigned short* q_b   = (unsigned short*)alloc(NODE_F * 2);
    unsigned short* kk_b  = (unsigned short*)alloc(NODE_F * 2);
    unsigned short* vv_b  = (unsigned short*)alloc(NODE_F * 2);
    unsigned short* oa_b  = (unsigned short*)alloc(NODE_F * 2);
    int* esrc   = (int*)alloc((size_t)E_TOT * 4);
    int* cnt    = (int*)alloc((size_t)NN * 4);
    int* base   = (int*)alloc((size_t)NN * 4);
    int* cursor = (int*)alloc((size_t)NN * 4);
    int* bsum   = (int*)alloc((size_t)SCAN_NB * 4);
    int2* meta2 = (int2*)alloc((size_t)NN * 8);
    unsigned short* F_u    = (unsigned short*)alloc(384 * 128 * 2);
    unsigned short* F_i    = (unsigned short*)alloc(384 * 128 * 2);
    float*          bias_u = (float*)alloc(384 * 4);
    float*          bias_i = (float*)alloc(384 * 4);
    unsigned short* Fo_u   = (unsigned short*)alloc(128 * 128 * 2);
    unsigned short* Fo_i   = (unsigned short*)alloc(128 * 128 * 2);

    // weight prep (fused launches, frag layout, f16)
    prep_kqv<<<768, 128, 0, stream>>>(W_kqv_user, b_kqv_user, W_kqv_item, b_kqv_item,
                                      Wk_rel, Wv_rel, F_u, bias_u, F_i, bias_i);
    prep_wo<<<128, 256, 0, stream>>>(W_out_user, Fo_u, W_out_item, Fo_i);

    // fused KQV(+rel) GEMM, both sides, LDS-free
    kqv_mfma<<<2 * KQV_NB, 256, 0, stream>>>(x_user, F_u, bias_u,
                                             x_item, F_i, bias_i,
                                             kk_b, q_b, vv_b);

    // CSR build
    hipMemsetAsync(cnt, 0, (size_t)NN * 4, stream);
    hist_kernel<<<(E_TOT + 255) / 256, 256, 0, stream>>>(edge_ui, edge_iu, cnt);
    scan1_kernel<<<SCAN_NB, 256, 0, stream>>>(cnt, base, bsum);
    scan3_kernel<<<(NN + 255) / 256, 256, 0, stream>>>(base, bsum, cnt, cursor, meta2);
    fill_kernel<<<(E_TOT + 255) / 256, 256, 0, stream>>>(edge_ui, edge_iu, cursor, esrc);

    attn_fused<<<2048, 256, 0, stream>>>(q_b, kk_b, vv_b, meta2, esrc,
                                         p_ui, p_iu, oa_b);

    // final GEMM, both sides, LDS-free (gelu already applied in attn)
    final_mfma<<<2 * KQV_NB, 256, 0, stream>>>(
        oa_b, x_user, Fo_u, b_out_user, skip_user,
        x_item, Fo_i, b_out_item, skip_item, (float*)d_out);
}